// Round 7
// baseline (53617.194 us; speedup 1.0000x reference)
//
#include <hip/hip_runtime.h>

// Inputs f32, outputs f32. f64 math end-to-end (top-k rank-gap ~3e-4 vs f32
// chain noise ~2e-6 -> swaps; R5 f64 PASS @ 9.8e-4 floor). R7: pre-converted
// f64 weights (kills 144 cvt/ic in conv3 loop) + Tier-Z2 staging (277MB).
// ws_size gates: A(814MB) > B(546MB) > Z2(277MB) > HI(8.64MB) > LO(R5, 4.43MB).

// ---- weight offsets (element offsets; same values for f32-lo / f64-hi) ----
#define WS_W1   0
#define WS_B1   288
#define WS_W2   320
#define WS_B2   18752
#define WS_W3   18816
#define WS_B3   92544
#define WS_FCW  92672
#define WS_FCB  125440
#define WS_G1W  125696
#define WS_G1B  256768
#define WS_L1G  257280
#define WS_L1B  257792
#define WS_G2W  258304
#define WS_G2B  520448
#define WS_L2G  520960
#define WS_L2B  521472
#define WS_G3W  521984
#define WS_G3B  526080
#define WS_END  526088
// ---- hi layout: f64 weights [0,526088) doubles; acc region follows ----
#define DH_ACC1 526088
// ---- lo layout (R5): f32 weights [0,526088) floats; acc at double off 263044
#define DL_ACC1 263044
#define ACC_ZN  553408   // doubles to zero from ACC1 (ACC1..AFF3 end)
// staging byte offsets (hi base ends at 1079496*8 = 8,635,968)
#define STG_OFF   8636416ull
#define Z2_BYTES  268435456ull
#define Z3_BYTES  536870912ull
#define NEED_HI   8635968ull
#define NEED_Z2   (STG_OFF + Z2_BYTES)
#define NEED_B    (STG_OFF + Z3_BYTES)
#define NEED_A    (STG_OFF + Z2_BYTES + Z3_BYTES)

// ---------------- zero f64 accumulator region ----------------
__global__ __launch_bounds__(256) void k_zero(double* __restrict__ dst){
  int i = blockIdx.x*256 + threadIdx.x;
  if(i < ACC_ZN) dst[i] = 0.0;
}

// ---------------- weight gather-copy ----------------
struct WP { const float* p[18]; };

template<typename WT>
__global__ __launch_bounds__(256) void k_cvt(WP wp, WT* __restrict__ dst){
  const int segn[18] = {288,32,18432,64,73728,128,32768,256,131072,512,512,512,262144,512,512,512,4096,8};
  const int sego[18] = {WS_W1,WS_B1,WS_W2,WS_B2,WS_W3,WS_B3,WS_FCW,WS_FCB,WS_G1W,WS_G1B,
                        WS_L1G,WS_L1B,WS_G2W,WS_G2B,WS_L2G,WS_L2B,WS_G3W,WS_G3B};
  int s = blockIdx.y;
  int i = blockIdx.x*256 + threadIdx.x;
  if(i < segn[s]) dst[sego[s]+i] = (WT)wp.p[s][i];
}

// ---------------- finalize BN stats: aff[2c]=scale, aff[2c+1]=shift ----------------
__global__ __launch_bounds__(64) void k_fin(const double* __restrict__ acc, int C,
                                            const float* __restrict__ gam, const float* __restrict__ bet,
                                            double* __restrict__ aff){
  int c = blockIdx.x, t = threadIdx.x;
  double s = acc[t*2*C + c*2];
  double q = acc[t*2*C + c*2 + 1];
  #pragma unroll
  for(int off=32;off;off>>=1){ s += __shfl_down(s,off); q += __shfl_down(q,off); }
  if(t==0){
    double m = s*(1.0/1048576.0);
    double v = q*(1.0/1048576.0) - m*m;
    double sc = (double)gam[c] / sqrt(v + 1e-5);
    aff[2*c]   = sc;
    aff[2*c+1] = (double)bet[c] - m*sc;
  }
}

// ---------------- pass 1: conv1 raw stats ----------------
template<typename WT>
__global__ __launch_bounds__(256) void k_p1(const float* __restrict__ x, const WT* __restrict__ wf,
                                            double* __restrict__ acc1){
  __shared__ float xp[324];
  __shared__ double red[4][32][2];
  int p = blockIdx.x, t = threadIdx.x;
  for(int i=t;i<324;i+=256) xp[i]=0.f;
  __syncthreads();
  int py=t>>4, px=t&15;
  xp[(py+1)*18 + px + 1] = x[(size_t)p*256+t];
  __syncthreads();
  double nb[9];
  #pragma unroll
  for(int j=0;j<9;j++) nb[j] = (double)xp[(py+j/3)*18 + px + (j%3)];
  int wave=t>>6, lane=t&63;
  for(int c=0;c<32;c++){
    double a = (double)wf[WS_B1+c];
    #pragma unroll
    for(int j=0;j<9;j++) a = fma(nb[j], (double)wf[WS_W1+c*9+j], a);
    double s=a, q=a*a;
    #pragma unroll
    for(int off=32;off;off>>=1){ s+=__shfl_down(s,off); q+=__shfl_down(q,off); }
    if(lane==0){ red[wave][c][0]=s; red[wave][c][1]=q; }
  }
  __syncthreads();
  if(t<64){
    int c=t>>1, st=t&1;
    double v = red[0][c][st]+red[1][c][st]+red[2][c][st]+red[3][c][st];
    atomicAdd(&acc1[(p&63)*64 + c*2 + st], v);
  }
}

// ========== staged: conv1 -> bn1relu -> conv2 -> z2 (f32) + stats ==========
template<typename WT>
__global__ __launch_bounds__(256) void k_s2(const float* __restrict__ x, const WT* __restrict__ wf,
                                            const double* __restrict__ aff1, double* __restrict__ acc2,
                                            float* __restrict__ z2){
  __shared__ float xp[324];
  __shared__ float h1f[32*324];
  __shared__ double red[4][32][2];
  int p=blockIdx.x, t=threadIdx.x;
  for(int i=t;i<324;i+=256) xp[i]=0.f;
  for(int i=t;i<32*324;i+=256) h1f[i]=0.f;
  __syncthreads();
  int py=t>>4, px=t&15;
  xp[(py+1)*18 + px + 1] = x[(size_t)p*256+t];
  __syncthreads();
  {
    double nb[9];
    #pragma unroll
    for(int j=0;j<9;j++) nb[j] = (double)xp[(py+j/3)*18 + px + (j%3)];
    for(int c=0;c<32;c++){
      double a = (double)wf[WS_B1+c];
      #pragma unroll
      for(int j=0;j<9;j++) a = fma(nb[j], (double)wf[WS_W1+c*9+j], a);
      h1f[c*324 + (py+1)*18 + (px+1)] = (float)fmax(aff1[2*c]*a + aff1[2*c+1], 0.0);
    }
  }
  __syncthreads();
  int wave=t>>6, lane=t&63;
  #pragma unroll 1
  for(int ot=0; ot<2; ++ot){
    double accs[32];
    #pragma unroll
    for(int o=0;o<32;o++) accs[o] = (double)wf[WS_B2+ot*32+o];
    #pragma unroll 1
    for(int ic=0;ic<32;ic++){
      double m[9];
      #pragma unroll
      for(int j=0;j<9;j++) m[j] = (double)h1f[ic*324 + (py+j/3)*18 + px + (j%3)];
      #pragma unroll
      for(int o=0;o<32;o++){
        #pragma unroll
        for(int j=0;j<9;j++) accs[o] = fma(m[j], (double)wf[WS_W2+((ot*32+o)*32+ic)*9+j], accs[o]);
      }
    }
    #pragma unroll
    for(int o=0;o<32;o++){
      int c = ot*32+o;
      z2[((size_t)p*64 + c)*256 + t] = (float)accs[o];
      double s=accs[o], q=accs[o]*accs[o];
      #pragma unroll
      for(int off=32;off;off>>=1){ s+=__shfl_down(s,off); q+=__shfl_down(q,off); }
      if(lane==0){ red[wave][o][0]=s; red[wave][o][1]=q; }
    }
    __syncthreads();
    if(t<64){
      int o=t>>1, st=t&1;
      double v = red[0][o][st]+red[1][o][st]+red[2][o][st]+red[3][o][st];
      atomicAdd(&acc2[(p&63)*128 + (ot*32+o)*2 + st], v);
    }
    __syncthreads();
  }
}

// ========== staged: z2 -> bn2relu strip -> conv3 -> stats (+z3 if WZ3) ==========
template<typename WT, int WZ3>
__global__ __launch_bounds__(256) void k_s3(const float* __restrict__ z2, const WT* __restrict__ wf,
                                            const double* __restrict__ aff2, double* __restrict__ acc3,
                                            float* __restrict__ z3){
  __shared__ float h2S[64*180];   // [ch][10 rows][18 cols]; row b <-> global row r0-1+b
  __shared__ double red[4][32][2];
  int bid=blockIdx.x, t=threadIdx.x;
  int p = bid>>1, r0 = (bid&1)*8;
  for(int i=t;i<64*180;i+=256) h2S[i]=0.f;
  __syncthreads();
  for(int i=t;i<10240;i+=256){
    int ch = i/160, rem = i - ch*160;
    int row = rem>>4, col = rem&15;
    int gr = r0 - 1 + row;
    if(gr>=0 && gr<16){
      double zv = (double)z2[((size_t)p*64 + ch)*256 + gr*16 + col];
      h2S[ch*180 + row*18 + col+1] = (float)fmax(fma(aff2[2*ch], zv, aff2[2*ch+1]), 0.0);
    }
  }
  __syncthreads();
  int pix=t&127, ocg=t>>7;
  int pr=pix>>4, col=pix&15;
  int wave=t>>6, lane=t&63;
  #pragma unroll 1
  for(int ot=0; ot<2; ++ot){
    int ocb = ot*64 + ocg*32;
    double accs[32];
    #pragma unroll
    for(int o=0;o<32;o++) accs[o] = (double)wf[WS_B3+ocb+o];
    #pragma unroll 1
    for(int ic=0;ic<64;ic++){
      double m[9];
      #pragma unroll
      for(int j=0;j<9;j++) m[j] = (double)h2S[ic*180 + (pr+j/3)*18 + col + (j%3)];
      #pragma unroll
      for(int o=0;o<32;o++){
        #pragma unroll
        for(int j=0;j<9;j++) accs[o] = fma(m[j], (double)wf[WS_W3+((ocb+o)*64+ic)*9+j], accs[o]);
      }
    }
    #pragma unroll
    for(int o=0;o<32;o++){
      if(WZ3) z3[((size_t)p*128 + ocb+o)*256 + (r0+pr)*16 + col] = (float)accs[o];
      double s=accs[o], q=accs[o]*accs[o];
      #pragma unroll
      for(int off=32;off;off>>=1){ s+=__shfl_down(s,off); q+=__shfl_down(q,off); }
      if(lane==0){ red[wave][o][0]=s; red[wave][o][1]=q; }
    }
    __syncthreads();
    if(t<128){
      int og=t>>6, o=(t>>1)&31, st=t&1;
      double v = red[og*2][o][st] + red[og*2+1][o][st];
      atomicAdd(&acc3[(bid&63)*256 + (ot*64+og*32+o)*2 + st], v);
    }
    __syncthreads();
  }
}

// ========== staged: z2 -> conv3 -> bn3relu -> spatial sum -> feat ==========
template<typename WT>
__global__ __launch_bounds__(256) void k_s3f(const float* __restrict__ z2, const WT* __restrict__ wf,
                                             const double* __restrict__ aff2, const double* __restrict__ aff3,
                                             double* __restrict__ feat){
  __shared__ float h2S[64*180];
  __shared__ double red[4][32];
  int bid=blockIdx.x, t=threadIdx.x;
  int p = bid>>1, r0 = (bid&1)*8;
  for(int i=t;i<64*180;i+=256) h2S[i]=0.f;
  __syncthreads();
  for(int i=t;i<10240;i+=256){
    int ch = i/160, rem = i - ch*160;
    int row = rem>>4, col = rem&15;
    int gr = r0 - 1 + row;
    if(gr>=0 && gr<16){
      double zv = (double)z2[((size_t)p*64 + ch)*256 + gr*16 + col];
      h2S[ch*180 + row*18 + col+1] = (float)fmax(fma(aff2[2*ch], zv, aff2[2*ch+1]), 0.0);
    }
  }
  __syncthreads();
  int pix=t&127, ocg=t>>7;
  int pr=pix>>4, col=pix&15;
  int wave=t>>6, lane=t&63;
  #pragma unroll 1
  for(int ot=0; ot<2; ++ot){
    int ocb = ot*64 + ocg*32;
    double accs[32];
    #pragma unroll
    for(int o=0;o<32;o++) accs[o] = (double)wf[WS_B3+ocb+o];
    #pragma unroll 1
    for(int ic=0;ic<64;ic++){
      double m[9];
      #pragma unroll
      for(int j=0;j<9;j++) m[j] = (double)h2S[ic*180 + (pr+j/3)*18 + col + (j%3)];
      #pragma unroll
      for(int o=0;o<32;o++){
        #pragma unroll
        for(int j=0;j<9;j++) accs[o] = fma(m[j], (double)wf[WS_W3+((ocb+o)*64+ic)*9+j], accs[o]);
      }
    }
    #pragma unroll
    for(int o=0;o<32;o++){
      int c = ocb+o;
      double v = fmax(aff3[2*c]*accs[o] + aff3[2*c+1], 0.0);
      #pragma unroll
      for(int off=32;off;off>>=1) v += __shfl_down(v,off);
      if(lane==0) red[wave][o]=v;
    }
    __syncthreads();
    if(t<64){
      int og=t>>5, o=t&31;
      double v = red[og*2][o] + red[og*2+1][o];
      atomicAdd(&feat[(size_t)p*128 + ot*64+og*32+o], v);
    }
    __syncthreads();
  }
}

// ========== staged: z3 -> bn3relu -> mean -> feat ==========
__global__ __launch_bounds__(256) void k_s4(const float* __restrict__ z3, const double* __restrict__ aff3,
                                            double* __restrict__ feat){
  int p=blockIdx.x, t=threadIdx.x;
  int wave=t>>6, lane=t&63;
  for(int c=wave; c<128; c+=4){
    const float* zp = z3 + ((size_t)p*128 + c)*256;
    double sc=aff3[2*c], sh=aff3[2*c+1];
    double s=0.0;
    #pragma unroll
    for(int k=0;k<4;k++){
      double zv = (double)zp[lane + 64*k];
      s += fmax(fma(sc, zv, sh), 0.0);
    }
    #pragma unroll
    for(int off=32;off;off>>=1) s += __shfl_down(s,off);
    if(lane==0) feat[(size_t)p*128 + c] = s;
  }
}

// ========== recompute: conv1 -> bn1relu -> conv2 raw stats ==========
template<typename WT>
__global__ __launch_bounds__(256) void k_p2(const float* __restrict__ x, const WT* __restrict__ wf,
                                            const double* __restrict__ aff1, double* __restrict__ acc2){
  __shared__ float xp[324];
  __shared__ float h1f[32*324];
  __shared__ double red[4][16][2];
  int p=blockIdx.x, t=threadIdx.x;
  for(int i=t;i<324;i+=256) xp[i]=0.f;
  __syncthreads();
  int py=t>>4, px=t&15;
  xp[(py+1)*18 + px + 1] = x[(size_t)p*256+t];
  __syncthreads();
  for(int i=t;i<32*324;i+=256) h1f[i]=0.f;
  __syncthreads();
  {
    double nb[9];
    #pragma unroll
    for(int j=0;j<9;j++) nb[j] = (double)xp[(py+j/3)*18 + px + (j%3)];
    for(int c=0;c<32;c++){
      double a = (double)wf[WS_B1+c];
      #pragma unroll
      for(int j=0;j<9;j++) a = fma(nb[j], (double)wf[WS_W1+c*9+j], a);
      h1f[c*324 + (py+1)*18 + (px+1)] = (float)fmax(aff1[2*c]*a + aff1[2*c+1], 0.0);
    }
  }
  __syncthreads();
  int wave=t>>6, lane=t&63;
  #pragma unroll 1
  for(int ot=0; ot<4; ++ot){
    double accs[16];
    #pragma unroll
    for(int o=0;o<16;o++) accs[o] = (double)wf[WS_B2+ot*16+o];
    #pragma unroll 1
    for(int ic=0;ic<32;ic++){
      double m[9];
      #pragma unroll
      for(int j=0;j<9;j++) m[j] = (double)h1f[ic*324 + (py+j/3)*18 + px + (j%3)];
      #pragma unroll
      for(int o=0;o<16;o++){
        #pragma unroll
        for(int j=0;j<9;j++) accs[o] = fma(m[j], (double)wf[WS_W2+((ot*16+o)*32+ic)*9+j], accs[o]);
      }
    }
    #pragma unroll
    for(int o=0;o<16;o++){
      double s=accs[o], q=accs[o]*accs[o];
      #pragma unroll
      for(int off=32;off;off>>=1){ s+=__shfl_down(s,off); q+=__shfl_down(q,off); }
      if(lane==0){ red[wave][o][0]=s; red[wave][o][1]=q; }
    }
    __syncthreads();
    if(t<32){
      int o=t>>1, st=t&1;
      double v = red[0][o][st]+red[1][o][st]+red[2][o][st]+red[3][o][st];
      atomicAdd(&acc2[(p&63)*128 + (ot*16+o)*2 + st], v);
    }
    __syncthreads();
  }
}

// ========== recompute strips: FM=0 stats, FM=1 feat, FM=2 stats+z3 ==========
template<typename WT, int FM>
__global__ __launch_bounds__(256) void k_p34(const float* __restrict__ x, const WT* __restrict__ wf,
                                             const double* __restrict__ aff1, const double* __restrict__ aff2,
                                             const double* __restrict__ aff3, double* __restrict__ outp,
                                             float* __restrict__ z3){
  __shared__ float xp[324];
  __shared__ float h1S[32*144];
  __shared__ float h2S[64*108];
  __shared__ double red[4][16][2];
  int bid=blockIdx.x, t=threadIdx.x;
  int p = bid>>2, r0 = (bid&3)*4;
  for(int i=t;i<324;i+=256) xp[i]=0.f;
  for(int i=t;i<32*144;i+=256) h1S[i]=0.f;
  for(int i=t;i<64*108;i+=256) h2S[i]=0.f;
  __syncthreads();
  { int py=t>>4, px=t&15; xp[(py+1)*18 + px + 1] = x[(size_t)p*256+t]; }
  __syncthreads();
  {
    int rr=t>>5, cw=t&31, col=cw&15, half=cw>>4;
    int p1 = r0-1+rr;
    if(p1>=1 && p1<=16){
      double nb[9];
      #pragma unroll
      for(int j=0;j<9;j++) nb[j] = (double)xp[(p1-1+j/3)*18 + col + (j%3)];
      for(int k=0;k<16;k++){
        int c = half*16+k;
        double a = (double)wf[WS_B1+c];
        #pragma unroll
        for(int j=0;j<9;j++) a = fma(nb[j], (double)wf[WS_W1+c*9+j], a);
        h1S[c*144 + rr*18 + col+1] = (float)fmax(aff1[2*c]*a + aff1[2*c+1], 0.0);
      }
    }
  }
  __syncthreads();
  {
    int col=t&15, g=t>>4;
    #pragma unroll 1
    for(int b2=0;b2<6;b2++){
      int p2 = r0+b2;
      if(p2>=1 && p2<=16){
        double a4[4];
        #pragma unroll
        for(int o=0;o<4;o++) a4[o] = (double)wf[WS_B2+g*4+o];
        #pragma unroll 1
        for(int ic=0;ic<32;ic++){
          double m[9];
          #pragma unroll
          for(int j=0;j<9;j++) m[j] = (double)h1S[ic*144 + (b2+j/3)*18 + col + (j%3)];
          #pragma unroll
          for(int o=0;o<4;o++){
            #pragma unroll
            for(int j=0;j<9;j++) a4[o] = fma(m[j], (double)wf[WS_W2+((g*4+o)*32+ic)*9+j], a4[o]);
          }
        }
        #pragma unroll
        for(int o=0;o<4;o++){
          int c=g*4+o;
          h2S[c*108 + b2*18 + col+1] = (float)fmax(aff2[2*c]*a4[o] + aff2[2*c+1], 0.0);
        }
      }
    }
  }
  __syncthreads();
  {
    int pix=t&63, ocb=t>>6;
    int pr=pix>>4, col=pix&15;
    int lane=t&63;
    #pragma unroll 1
    for(int ot=0; ot<2; ++ot){
      double accs[16];
      #pragma unroll
      for(int o=0;o<16;o++) accs[o] = (double)wf[WS_B3+ocb*32+ot*16+o];
      #pragma unroll 1
      for(int ic=0;ic<64;ic++){
        double m[9];
        #pragma unroll
        for(int j=0;j<9;j++) m[j] = (double)h2S[ic*108 + (pr+j/3)*18 + col + (j%3)];
        #pragma unroll
        for(int o=0;o<16;o++){
          #pragma unroll
          for(int j=0;j<9;j++) accs[o] = fma(m[j], (double)wf[WS_W3+((ocb*32+ot*16+o)*64+ic)*9+j], accs[o]);
        }
      }
      if(FM==0 || FM==2){
        if(FM==2){
          #pragma unroll
          for(int o=0;o<16;o++){
            int c = ocb*32+ot*16+o;
            z3[((size_t)p*128 + c)*256 + (r0+pr)*16 + col] = (float)accs[o];
          }
        }
        #pragma unroll
        for(int o=0;o<16;o++){
          double s=accs[o], q=accs[o]*accs[o];
          #pragma unroll
          for(int off=32;off;off>>=1){ s+=__shfl_down(s,off); q+=__shfl_down(q,off); }
          if(lane==0){ red[ocb][o][0]=s; red[ocb][o][1]=q; }
        }
        __syncthreads();
        if(t<128){
          int idx=t>>1, st=t&1;
          int ob=idx>>4, o=idx&15;
          int c = ob*32 + ot*16 + o;
          atomicAdd(&outp[(bid&63)*256 + c*2 + st], red[ob][o][st]);
        }
        __syncthreads();
      } else {
        #pragma unroll
        for(int o=0;o<16;o++){
          int c = ocb*32+ot*16+o;
          double v = fmax(aff3[2*c]*accs[o] + aff3[2*c+1], 0.0);
          #pragma unroll
          for(int off=32;off;off>>=1) v += __shfl_down(v,off);
          if(lane==0) red[ocb][o][0]=v;
        }
        __syncthreads();
        if(t<64){
          int ob=t>>4, o=t&15;
          int c = ob*32 + ot*16 + o;
          atomicAdd(&outp[(size_t)p*128 + c], red[ob][o][0]);
        }
        __syncthreads();
      }
    }
  }
}

// ---------------- LN + relu on [4][512] f64 LDS buffer ----------------
template<typename WT>
__device__ __forceinline__ void ln_relu4(double* buf, const WT* __restrict__ g, const WT* __restrict__ b,
                                         double* lnm, double* lnr, int t){
  int r=t>>6, j=t&63;
  double s=0.0, q=0.0;
  for(int k=j;k<512;k+=64){ double v=buf[r*512+k]; s+=v; q+=v*v; }
  #pragma unroll
  for(int off=32;off;off>>=1){ s+=__shfl_down(s,off); q+=__shfl_down(q,off); }
  if(j==0){
    double m = s*(1.0/512.0);
    double v = q*(1.0/512.0) - m*m;
    lnm[r]=m; lnr[r]=1.0/sqrt(v + 1e-5);
  }
  __syncthreads();
  for(int i=t;i<2048;i+=256){
    int r2=i>>9, k=i&511;
    double v=(buf[i]-lnm[r2])*lnr[r2]*(double)g[k]+(double)b[k];
    buf[i]=fmax(v,0.0);
  }
  __syncthreads();
}

// ---------------- MLP head (f64): feat -> assignment f32 ----------------
template<typename WT>
__global__ __launch_bounds__(256) void k_mlp(const WT* __restrict__ wf, const double* __restrict__ feat,
                                             float* __restrict__ assign_out){
  int r0 = blockIdx.x*4, t = threadIdx.x;
  __shared__ double f0[4*128];
  __shared__ double f1[4*256];
  __shared__ double f2[4*512];
  __shared__ double f3[4*512];
  __shared__ double lnm[4], lnr[4];
  __shared__ double lg[4][8];

  for(int i=t;i<512;i+=256) f0[i] = feat[(size_t)r0*128 + i] * (1.0/256.0);
  __syncthreads();
  {
    double acc[4];
    double bv = (double)wf[WS_FCB + t];
    #pragma unroll
    for(int r=0;r<4;r++) acc[r]=bv;
    for(int k=0;k<128;k++){
      double wv = (double)wf[WS_FCW + t*128 + k];
      #pragma unroll
      for(int r=0;r<4;r++) acc[r]=fma(wv, f0[r*128+k], acc[r]);
    }
    #pragma unroll
    for(int r=0;r<4;r++) f1[r*256+t]=acc[r];
  }
  __syncthreads();
  for(int half=0;half<2;half++){
    int i=t+(half<<8);
    double acc[4];
    double bv=(double)wf[WS_G1B+i];
    #pragma unroll
    for(int r=0;r<4;r++) acc[r]=bv;
    for(int k=0;k<256;k++){
      double wv=(double)wf[WS_G1W + i*256 + k];
      #pragma unroll
      for(int r=0;r<4;r++) acc[r]=fma(wv, f1[r*256+k], acc[r]);
    }
    #pragma unroll
    for(int r=0;r<4;r++) f2[r*512+i]=acc[r];
  }
  __syncthreads();
  ln_relu4(f2, wf+WS_L1G, wf+WS_L1B, lnm, lnr, t);
  for(int half=0;half<2;half++){
    int i=t+(half<<8);
    double acc[4];
    double bv=(double)wf[WS_G2B+i];
    #pragma unroll
    for(int r=0;r<4;r++) acc[r]=bv;
    for(int k=0;k<512;k++){
      double wv=(double)wf[WS_G2W + i*512 + k];
      #pragma unroll
      for(int r=0;r<4;r++) acc[r]=fma(wv, f2[r*512+k], acc[r]);
    }
    #pragma unroll
    for(int r=0;r<4;r++) f3[r*512+i]=acc[r];
  }
  __syncthreads();
  ln_relu4(f3, wf+WS_L2G, wf+WS_L2B, lnm, lnr, t);
  {
    int r=t>>6, j=t&63;
    double pl[8];
    #pragma unroll
    for(int g=0;g<8;g++){
      double s=0.0;
      for(int k=j;k<512;k+=64) s = fma(f3[r*512+k], (double)wf[WS_G3W + g*512 + k], s);
      pl[g]=s;
    }
    #pragma unroll
    for(int off=32;off;off>>=1){
      #pragma unroll
      for(int g=0;g<8;g++) pl[g] += __shfl_down(pl[g], off);
    }
    if(j==0){
      #pragma unroll
      for(int g=0;g<8;g++) lg[r][g] = (pl[g] + (double)wf[WS_G3B+g]) * 2.0; // /TEMP
    }
  }
  __syncthreads();
  if(t<4){
    double m=-1e300;
    #pragma unroll
    for(int g=0;g<8;g++) m = fmax(m, lg[t][g]);
    double e[8], s=0.0;
    #pragma unroll
    for(int g=0;g<8;g++){ e[g]=exp(lg[t][g]-m); s+=e[g]; }
    double inv = 1.0/s;
    int row = r0 + t;
    #pragma unroll
    for(int g=0;g<8;g++) assign_out[row*8+g] = (float)(e[g]*inv);
  }
}

// ---------------- top-32 per (b,g) + gather*scale ----------------
__global__ __launch_bounds__(256) void k_topk(const float* __restrict__ assign, const float* __restrict__ x,
                                              float* __restrict__ out){
  int b = blockIdx.x >> 3, g = blockIdx.x & 7, t = threadIdx.x;
  __shared__ float v[256];
  __shared__ int   id[256];
  v[t] = assign[(b*256+t)*8 + g];
  id[t] = t;
  __syncthreads();
  for(int k=2;k<=256;k<<=1){
    for(int j=k>>1;j>0;j>>=1){
      int ixj = t ^ j;
      if(ixj > t){
        float va=v[t], vb=v[ixj];
        int ia=id[t], ib=id[ixj];
        bool aBefore = (va > vb) || (va == vb && ia < ib);
        bool up = ((t & k) == 0);
        if(up != aBefore){ v[t]=vb; v[ixj]=va; id[t]=ib; id[ixj]=ia; }
      }
      __syncthreads();
    }
  }
  __shared__ float tv[32];
  __shared__ int   ti[32];
  if(t<32){ tv[t]=v[t]; ti[t]=id[t]; }
  __syncthreads();
  const float* xb = x + (size_t)b*65536;
  float* ob = out + (size_t)(b*8+g)*8192;
  for(int i=t;i<8192;i+=256){
    int k=i>>8, pix=i&255;
    ob[i] = tv[k] * xb[ti[k]*256 + pix];
  }
}

// ---------------- launcher ----------------
extern "C" void kernel_launch(void* const* d_in, const int* in_sizes, int n_in,
                              void* d_out, int out_size, void* d_ws, size_t ws_size,
                              hipStream_t stream){
  const float* x = (const float*)d_in[0];
  float*  ws  = (float*)d_ws;
  double* dws = (double*)d_ws;
  float* out = (float*)d_out;
  float* assign_out = out + 1048576;

  const float* g1=(const float*)d_in[3];  const float* b1=(const float*)d_in[4];
  const float* g2=(const float*)d_in[7];  const float* b2=(const float*)d_in[8];
  const float* g3=(const float*)d_in[11]; const float* b3=(const float*)d_in[12];

  WP wp;
  const int map[18] = {1,2,5,6,9,10,13,14,15,16,17,18,19,20,21,22,23,24};
  for(int i=0;i<18;i++) wp.p[i] = (const float*)d_in[map[i]];

  bool hi = ws_size >= NEED_HI;
  double* ACC1 = dws + (hi ? DH_ACC1 : DL_ACC1);
  double* ACC2 = ACC1 + 4096;
  double* ACC3 = ACC2 + 8192;
  double* FEAT = ACC3 + 16384;
  double* AFF1 = FEAT + 524288;
  double* AFF2 = AFF1 + 64;
  double* AFF3 = AFF2 + 128;
  float* z2  = (float*)((char*)d_ws + STG_OFF);
  float* z3a = (float*)((char*)d_ws + STG_OFF + Z2_BYTES);
  float* z3b = (float*)((char*)d_ws + STG_OFF);

  k_zero<<<2162, 256, 0, stream>>>(ACC1);

  if(hi){
    k_cvt<double><<<dim3(1024,18), 256, 0, stream>>>(wp, dws);
    k_p1<double><<<4096, 256, 0, stream>>>(x, dws, ACC1);
    k_fin<<<32, 64, 0, stream>>>(ACC1, 32, g1, b1, AFF1);
    if(ws_size >= NEED_A){
      k_s2<double><<<4096, 256, 0, stream>>>(x, dws, AFF1, ACC2, z2);
      k_fin<<<64, 64, 0, stream>>>(ACC2, 64, g2, b2, AFF2);
      k_s3<double,1><<<8192, 256, 0, stream>>>(z2, dws, AFF2, ACC3, z3a);
      k_fin<<<128, 64, 0, stream>>>(ACC3, 128, g3, b3, AFF3);
      k_s4<<<4096, 256, 0, stream>>>(z3a, AFF3, FEAT);
    } else if(ws_size >= NEED_B){
      k_p2<double><<<4096, 256, 0, stream>>>(x, dws, AFF1, ACC2);
      k_fin<<<64, 64, 0, stream>>>(ACC2, 64, g2, b2, AFF2);
      k_p34<double,2><<<16384, 256, 0, stream>>>(x, dws, AFF1, AFF2, AFF3, ACC3, z3b);
      k_fin<<<128, 64, 0, stream>>>(ACC3, 128, g3, b3, AFF3);
      k_s4<<<4096, 256, 0, stream>>>(z3b, AFF3, FEAT);
    } else if(ws_size >= NEED_Z2){
      k_s2<double><<<4096, 256, 0, stream>>>(x, dws, AFF1, ACC2, z2);
      k_fin<<<64, 64, 0, stream>>>(ACC2, 64, g2, b2, AFF2);
      k_s3<double,0><<<8192, 256, 0, stream>>>(z2, dws, AFF2, ACC3, nullptr);
      k_fin<<<128, 64, 0, stream>>>(ACC3, 128, g3, b3, AFF3);
      k_s3f<double><<<8192, 256, 0, stream>>>(z2, dws, AFF2, AFF3, FEAT);
    } else {
      k_p2<double><<<4096, 256, 0, stream>>>(x, dws, AFF1, ACC2);
      k_fin<<<64, 64, 0, stream>>>(ACC2, 64, g2, b2, AFF2);
      k_p34<double,0><<<16384, 256, 0, stream>>>(x, dws, AFF1, AFF2, AFF3, ACC3, nullptr);
      k_fin<<<128, 64, 0, stream>>>(ACC3, 128, g3, b3, AFF3);
      k_p34<double,1><<<16384, 256, 0, stream>>>(x, dws, AFF1, AFF2, AFF3, FEAT, nullptr);
    }
    k_mlp<double><<<1024, 256, 0, stream>>>(dws, FEAT, assign_out);
  } else {
    // lo fallback: R5 layout (f32 weights + per-use cvt)
    k_cvt<float><<<dim3(1024,18), 256, 0, stream>>>(wp, ws);
    k_p1<float><<<4096, 256, 0, stream>>>(x, ws, ACC1);
    k_fin<<<32, 64, 0, stream>>>(ACC1, 32, g1, b1, AFF1);
    k_p2<float><<<4096, 256, 0, stream>>>(x, ws, AFF1, ACC2);
    k_fin<<<64, 64, 0, stream>>>(ACC2, 64, g2, b2, AFF2);
    k_p34<float,0><<<16384, 256, 0, stream>>>(x, ws, AFF1, AFF2, AFF3, ACC3, nullptr);
    k_fin<<<128, 64, 0, stream>>>(ACC3, 128, g3, b3, AFF3);
    k_p34<float,1><<<16384, 256, 0, stream>>>(x, ws, AFF1, AFF2, AFF3, FEAT, nullptr);
    k_mlp<float><<<1024, 256, 0, stream>>>(ws, FEAT, assign_out);
  }
  k_topk<<<128, 256, 0, stream>>>(assign_out, x, out);
}

// Round 8
// 11084.413 us; speedup vs baseline: 4.8372x; 4.8372x over previous
//
#include <hip/hip_runtime.h>

// Inputs f32, outputs f32. f64 MAC arithmetic end-to-end (top-k rank gaps at
// rank-32 boundary ~1e-6..3e-4; f32-chain noise causes swaps -> R4 fail; f64
// passes at the bf16-ulp floor). Weights kept f32 in ws (R7 showed f64 weights
// stall on the scalar/L1 weight stream: VALUBusy 53%->15%, 2x slower).
// R8: register-block conv3 (4 px x 8 oc per thread) so each weight load+cvt
// feeds 4 FMAs instead of 1; hoist conv2 weight cvts out of the row loop.
// Known: ws_size in [8.6 MB, 277 MB) -> no z2/z3 staging possible; this uses
// only ~6.5 MB.

// ---- f32 weight block (float offsets into ws) ----
#define WS_W1   0
#define WS_B1   288
#define WS_W2   320
#define WS_B2   18752
#define WS_W3   18816
#define WS_B3   92544
#define WS_FCW  92672
#define WS_FCB  125440
#define WS_G1W  125696
#define WS_G1B  256768
#define WS_L1G  257280
#define WS_L1B  257792
#define WS_G2W  258304
#define WS_G2B  520448
#define WS_L2G  520960
#define WS_L2B  521472
#define WS_G3W  521984
#define WS_G3B  526080
// ---- f64 region (double offsets into ws) ----
#define D_ACC1  263044                 // 64 buckets x 32ch x 2
#define D_ACC2  (D_ACC1 + 4096)       // 64 x 64 x 2
#define D_ACC3  (D_ACC2 + 8192)       // 64 x 128 x 2
#define D_FEAT  (D_ACC3 + 16384)      // 4096 x 128
#define D_AFF1  (D_FEAT + 524288)
#define D_AFF2  (D_AFF1 + 64)
#define D_AFF3  (D_AFF2 + 128)
#define D_ZN    553408                 // doubles to zero from D_ACC1

// ---------------- zero f64 accumulators ----------------
__global__ __launch_bounds__(256) void k_zero(double* __restrict__ dst){
  int i = blockIdx.x*256 + threadIdx.x;
  if(i < D_ZN) dst[i] = 0.0;
}

// ---------------- weight gather-copy (f32) ----------------
struct WP { const float* p[18]; };

__global__ __launch_bounds__(256) void k_cvt(WP wp, float* __restrict__ dst){
  const int segn[18] = {288,32,18432,64,73728,128,32768,256,131072,512,512,512,262144,512,512,512,4096,8};
  const int sego[18] = {WS_W1,WS_B1,WS_W2,WS_B2,WS_W3,WS_B3,WS_FCW,WS_FCB,WS_G1W,WS_G1B,
                        WS_L1G,WS_L1B,WS_G2W,WS_G2B,WS_L2G,WS_L2B,WS_G3W,WS_G3B};
  int s = blockIdx.y;
  int i = blockIdx.x*256 + threadIdx.x;
  if(i < segn[s]) dst[sego[s]+i] = wp.p[s][i];
}

// ---------------- finalize BN stats: aff[2c]=scale, aff[2c+1]=shift ----------------
__global__ __launch_bounds__(64) void k_fin(const double* __restrict__ acc, int C,
                                            const float* __restrict__ gam, const float* __restrict__ bet,
                                            double* __restrict__ aff){
  int c = blockIdx.x, t = threadIdx.x;
  double s = acc[t*2*C + c*2];
  double q = acc[t*2*C + c*2 + 1];
  #pragma unroll
  for(int off=32;off;off>>=1){ s += __shfl_down(s,off); q += __shfl_down(q,off); }
  if(t==0){
    double m = s*(1.0/1048576.0);
    double v = q*(1.0/1048576.0) - m*m;
    double sc = (double)gam[c] / sqrt(v + 1e-5);
    aff[2*c]   = sc;
    aff[2*c+1] = (double)bet[c] - m*sc;
  }
}

// ---------------- pass 1: conv1 raw stats ----------------
__global__ __launch_bounds__(256) void k_p1(const float* __restrict__ x, const float* __restrict__ wf,
                                            double* __restrict__ acc1){
  __shared__ float xp[324];
  __shared__ double red[4][32][2];
  int p = blockIdx.x, t = threadIdx.x;
  for(int i=t;i<324;i+=256) xp[i]=0.f;
  __syncthreads();
  int py=t>>4, px=t&15;
  xp[(py+1)*18 + px + 1] = x[(size_t)p*256+t];
  __syncthreads();
  double nb[9];
  #pragma unroll
  for(int j=0;j<9;j++) nb[j] = (double)xp[(py+j/3)*18 + px + (j%3)];
  int wave=t>>6, lane=t&63;
  for(int c=0;c<32;c++){
    double a = (double)wf[WS_B1+c];
    #pragma unroll
    for(int j=0;j<9;j++) a = fma(nb[j], (double)wf[WS_W1+c*9+j], a);
    double s=a, q=a*a;
    #pragma unroll
    for(int off=32;off;off>>=1){ s+=__shfl_down(s,off); q+=__shfl_down(q,off); }
    if(lane==0){ red[wave][c][0]=s; red[wave][c][1]=q; }
  }
  __syncthreads();
  if(t<64){
    int c=t>>1, st=t&1;
    double v = red[0][c][st]+red[1][c][st]+red[2][c][st]+red[3][c][st];
    atomicAdd(&acc1[(p&63)*64 + c*2 + st], v);
  }
}

// ---------------- pass 2: conv1 -> bn1relu -> conv2 raw stats ----------------
__global__ __launch_bounds__(256) void k_p2(const float* __restrict__ x, const float* __restrict__ wf,
                                            const double* __restrict__ aff1, double* __restrict__ acc2){
  __shared__ float xp[324];
  __shared__ float h1f[32*324];
  __shared__ double red[4][16][2];
  int p=blockIdx.x, t=threadIdx.x;
  for(int i=t;i<324;i+=256) xp[i]=0.f;
  __syncthreads();
  int py=t>>4, px=t&15;
  xp[(py+1)*18 + px + 1] = x[(size_t)p*256+t];
  __syncthreads();
  for(int i=t;i<32*324;i+=256) h1f[i]=0.f;
  __syncthreads();
  {
    double nb[9];
    #pragma unroll
    for(int j=0;j<9;j++) nb[j] = (double)xp[(py+j/3)*18 + px + (j%3)];
    for(int c=0;c<32;c++){
      double a = (double)wf[WS_B1+c];
      #pragma unroll
      for(int j=0;j<9;j++) a = fma(nb[j], (double)wf[WS_W1+c*9+j], a);
      h1f[c*324 + (py+1)*18 + (px+1)] = (float)fmax(aff1[2*c]*a + aff1[2*c+1], 0.0);
    }
  }
  __syncthreads();
  int wave=t>>6, lane=t&63;
  #pragma unroll 1
  for(int ot=0; ot<4; ++ot){
    double accs[16];
    #pragma unroll
    for(int o=0;o<16;o++) accs[o] = (double)wf[WS_B2+ot*16+o];
    #pragma unroll 1
    for(int ic=0;ic<32;ic++){
      double m[9];
      #pragma unroll
      for(int j=0;j<9;j++) m[j] = (double)h1f[ic*324 + (py+j/3)*18 + px + (j%3)];
      #pragma unroll
      for(int o=0;o<16;o++){
        #pragma unroll
        for(int j=0;j<9;j++) accs[o] = fma(m[j], (double)wf[WS_W2+((ot*16+o)*32+ic)*9+j], accs[o]);
      }
    }
    #pragma unroll
    for(int o=0;o<16;o++){
      double s=accs[o], q=accs[o]*accs[o];
      #pragma unroll
      for(int off=32;off;off>>=1){ s+=__shfl_down(s,off); q+=__shfl_down(q,off); }
      if(lane==0){ red[wave][o][0]=s; red[wave][o][1]=q; }
    }
    __syncthreads();
    if(t<32){
      int o=t>>1, st=t&1;
      double v = red[0][o][st]+red[1][o][st]+red[2][o][st]+red[3][o][st];
      atomicAdd(&acc2[(p&63)*128 + (ot*16+o)*2 + st], v);
    }
    __syncthreads();
  }
}

// ---------------- pass 3/4: 4-row strips; register-blocked conv3 ----------------
// FM=0: conv3 raw stats -> ACC3 (bucketed). FM=1: bn3relu + spatial sum -> FEAT.
template<int FM>
__global__ __launch_bounds__(256) void k_p34(const float* __restrict__ x, const float* __restrict__ wf,
                                             const double* __restrict__ aff1, const double* __restrict__ aff2,
                                             const double* __restrict__ aff3, double* __restrict__ outp){
  __shared__ float xp[324];
  __shared__ float h1S[32*144];   // [ch][8 rows][18 cols]; row rr <-> padded row r0-1+rr
  __shared__ float h2S[64*108];   // [ch][6 rows][18 cols]; row b2 <-> padded row r0+b2
  int bid=blockIdx.x, t=threadIdx.x;
  int p = bid>>2, r0 = (bid&3)*4;
  for(int i=t;i<324;i+=256) xp[i]=0.f;
  for(int i=t;i<32*144;i+=256) h1S[i]=0.f;
  for(int i=t;i<64*108;i+=256) h2S[i]=0.f;
  __syncthreads();
  { int py=t>>4, px=t&15; xp[(py+1)*18 + px + 1] = x[(size_t)p*256+t]; }
  __syncthreads();
  // ---- h1 strip: padded rows r0-1 .. r0+6 ----
  {
    int rr=t>>5, cw=t&31, col=cw&15, half=cw>>4;
    int p1 = r0-1+rr;
    if(p1>=1 && p1<=16){
      double nb[9];
      #pragma unroll
      for(int j=0;j<9;j++) nb[j] = (double)xp[(p1-1+j/3)*18 + col + (j%3)];
      for(int k=0;k<16;k++){
        int c = half*16+k;
        double a = (double)wf[WS_B1+c];
        #pragma unroll
        for(int j=0;j<9;j++) a = fma(nb[j], (double)wf[WS_W1+c*9+j], a);
        h1S[c*144 + rr*18 + col+1] = (float)fmax(aff1[2*c]*a + aff1[2*c+1], 0.0);
      }
    }
  }
  __syncthreads();
  // ---- h2 strip: padded rows r0 .. r0+5; thread = (col, 4-oc group) x 6 rows ----
  // weight cvts hoisted out of the row loop; compute ungated, store gated.
  {
    int col=t&15, g=t>>4;
    double a24[4][6];
    #pragma unroll
    for(int o=0;o<4;o++){
      double bv = (double)wf[WS_B2+g*4+o];
      #pragma unroll
      for(int b2=0;b2<6;b2++) a24[o][b2] = bv;
    }
    #pragma unroll 1
    for(int ic=0;ic<32;ic++){
      double w4[4][9];
      #pragma unroll
      for(int o=0;o<4;o++){
        #pragma unroll
        for(int j=0;j<9;j++) w4[o][j] = (double)wf[WS_W2+((g*4+o)*32+ic)*9+j];
      }
      #pragma unroll
      for(int b2=0;b2<6;b2++){
        double m[9];
        #pragma unroll
        for(int j=0;j<9;j++) m[j] = (double)h1S[ic*144 + (b2+j/3)*18 + col + (j%3)];
        #pragma unroll
        for(int o=0;o<4;o++){
          #pragma unroll
          for(int j=0;j<9;j++) a24[o][b2] = fma(m[j], w4[o][j], a24[o][b2]);
        }
      }
    }
    #pragma unroll
    for(int b2=0;b2<6;b2++){
      int p2 = r0+b2;
      if(p2>=1 && p2<=16){
        #pragma unroll
        for(int o=0;o<4;o++){
          int c=g*4+o;
          h2S[c*108 + b2*18 + col+1] = (float)fmax(aff2[2*c]*a24[o][b2] + aff2[2*c+1], 0.0);
        }
      }
    }
  }
  __syncthreads();
  // ---- conv3: all 128 oc in one pass; thread = (col, 8-oc group) x 4 rows ----
  {
    int col = t & 15, og = t >> 4;    // og in 0..15
    double acc[8][4];
    #pragma unroll
    for(int o=0;o<8;o++){
      double bv = (double)wf[WS_B3 + og*8 + o];
      #pragma unroll
      for(int r=0;r<4;r++) acc[o][r] = bv;
    }
    #pragma unroll 1
    for(int ic=0; ic<64; ++ic){
      double a[6][3];
      #pragma unroll
      for(int rr=0; rr<6; ++rr){
        #pragma unroll
        for(int dx=0; dx<3; ++dx) a[rr][dx] = (double)h2S[ic*108 + rr*18 + col + dx];
      }
      const float* wrow = wf + WS_W3 + (og*8*64 + ic)*9;   // oc stride = 64*9 = 576
      #pragma unroll
      for(int o=0;o<8;o++){
        #pragma unroll
        for(int j=0;j<9;j++){
          double w = (double)wrow[o*576 + j];
          #pragma unroll
          for(int r=0;r<4;r++) acc[o][r] = fma(a[r + j/3][j%3], w, acc[o][r]);
        }
      }
    }
    if(FM==0){
      #pragma unroll
      for(int o=0;o<8;o++){
        double s = acc[o][0]+acc[o][1]+acc[o][2]+acc[o][3];
        double q = acc[o][0]*acc[o][0]+acc[o][1]*acc[o][1]
                 + acc[o][2]*acc[o][2]+acc[o][3]*acc[o][3];
        #pragma unroll
        for(int off=8; off; off>>=1){ s += __shfl_down(s, off, 16); q += __shfl_down(q, off, 16); }
        if(col==0){
          int c = og*8+o;
          atomicAdd(&outp[(bid&63)*256 + c*2 + 0], s);
          atomicAdd(&outp[(bid&63)*256 + c*2 + 1], q);
        }
      }
    } else {
      #pragma unroll
      for(int o=0;o<8;o++){
        int c = og*8+o;
        double sc=aff3[2*c], sh=aff3[2*c+1];
        double s = 0.0;
        #pragma unroll
        for(int r=0;r<4;r++) s += fmax(fma(sc, acc[o][r], sh), 0.0);
        #pragma unroll
        for(int off=8; off; off>>=1) s += __shfl_down(s, off, 16);
        if(col==0) atomicAdd(&outp[(size_t)p*128 + c], s);
      }
    }
  }
}

// ---------------- LN + relu on [4][512] f64 LDS buffer ----------------
__device__ __forceinline__ void ln_relu4(double* buf, const float* __restrict__ g, const float* __restrict__ b,
                                         double* lnm, double* lnr, int t){
  int r=t>>6, j=t&63;
  double s=0.0, q=0.0;
  for(int k=j;k<512;k+=64){ double v=buf[r*512+k]; s+=v; q+=v*v; }
  #pragma unroll
  for(int off=32;off;off>>=1){ s+=__shfl_down(s,off); q+=__shfl_down(q,off); }
  if(j==0){
    double m = s*(1.0/512.0);
    double v = q*(1.0/512.0) - m*m;
    lnm[r]=m; lnr[r]=1.0/sqrt(v + 1e-5);
  }
  __syncthreads();
  for(int i=t;i<2048;i+=256){
    int r2=i>>9, k=i&511;
    double v=(buf[i]-lnm[r2])*lnr[r2]*(double)g[k]+(double)b[k];
    buf[i]=fmax(v,0.0);
  }
  __syncthreads();
}

// ---------------- MLP head (f64): feat -> assignment f32 (4 rows/block) ----------------
__global__ __launch_bounds__(256) void k_mlp(const float* __restrict__ wf, const double* __restrict__ feat,
                                             float* __restrict__ assign_out){
  int r0 = blockIdx.x*4, t = threadIdx.x;
  __shared__ double f0[4*128];
  __shared__ double f1[4*256];
  __shared__ double f2[4*512];
  __shared__ double f3[4*512];
  __shared__ double lnm[4], lnr[4];
  __shared__ double lg[4][8];

  for(int i=t;i<512;i+=256) f0[i] = feat[(size_t)r0*128 + i] * (1.0/256.0);
  __syncthreads();
  {
    double acc[4];
    double bv = (double)wf[WS_FCB + t];
    #pragma unroll
    for(int r=0;r<4;r++) acc[r]=bv;
    for(int k=0;k<128;k++){
      double wv = (double)wf[WS_FCW + t*128 + k];
      #pragma unroll
      for(int r=0;r<4;r++) acc[r]=fma(wv, f0[r*128+k], acc[r]);
    }
    #pragma unroll
    for(int r=0;r<4;r++) f1[r*256+t]=acc[r];
  }
  __syncthreads();
  for(int half=0;half<2;half++){
    int i=t+(half<<8);
    double acc[4];
    double bv=(double)wf[WS_G1B+i];
    #pragma unroll
    for(int r=0;r<4;r++) acc[r]=bv;
    for(int k=0;k<256;k++){
      double wv=(double)wf[WS_G1W + i*256 + k];
      #pragma unroll
      for(int r=0;r<4;r++) acc[r]=fma(wv, f1[r*256+k], acc[r]);
    }
    #pragma unroll
    for(int r=0;r<4;r++) f2[r*512+i]=acc[r];
  }
  __syncthreads();
  ln_relu4(f2, wf+WS_L1G, wf+WS_L1B, lnm, lnr, t);
  for(int half=0;half<2;half++){
    int i=t+(half<<8);
    double acc[4];
    double bv=(double)wf[WS_G2B+i];
    #pragma unroll
    for(int r=0;r<4;r++) acc[r]=bv;
    for(int k=0;k<512;k++){
      double wv=(double)wf[WS_G2W + i*512 + k];
      #pragma unroll
      for(int r=0;r<4;r++) acc[r]=fma(wv, f2[r*512+k], acc[r]);
    }
    #pragma unroll
    for(int r=0;r<4;r++) f3[r*512+i]=acc[r];
  }
  __syncthreads();
  ln_relu4(f3, wf+WS_L2G, wf+WS_L2B, lnm, lnr, t);
  {
    int r=t>>6, j=t&63;
    double pl[8];
    #pragma unroll
    for(int g=0;g<8;g++){
      double s=0.0;
      for(int k=j;k<512;k+=64) s = fma(f3[r*512+k], (double)wf[WS_G3W + g*512 + k], s);
      pl[g]=s;
    }
    #pragma unroll
    for(int off=32;off;off>>=1){
      #pragma unroll
      for(int g=0;g<8;g++) pl[g] += __shfl_down(pl[g], off);
    }
    if(j==0){
      #pragma unroll
      for(int g=0;g<8;g++) lg[r][g] = (pl[g] + (double)wf[WS_G3B+g]) * 2.0; // /TEMP
    }
  }
  __syncthreads();
  if(t<4){
    double m=-1e300;
    #pragma unroll
    for(int g=0;g<8;g++) m = fmax(m, lg[t][g]);
    double e[8], s=0.0;
    #pragma unroll
    for(int g=0;g<8;g++){ e[g]=exp(lg[t][g]-m); s+=e[g]; }
    double inv = 1.0/s;
    int row = r0 + t;
    #pragma unroll
    for(int g=0;g<8;g++) assign_out[row*8+g] = (float)(e[g]*inv);
  }
}

// ---------------- top-32 per (b,g) + gather*scale ----------------
__global__ __launch_bounds__(256) void k_topk(const float* __restrict__ assign, const float* __restrict__ x,
                                              float* __restrict__ out){
  int b = blockIdx.x >> 3, g = blockIdx.x & 7, t = threadIdx.x;
  __shared__ float v[256];
  __shared__ int   id[256];
  v[t] = assign[(b*256+t)*8 + g];
  id[t] = t;
  __syncthreads();
  for(int k=2;k<=256;k<<=1){
    for(int j=k>>1;j>0;j>>=1){
      int ixj = t ^ j;
      if(ixj > t){
        float va=v[t], vb=v[ixj];
        int ia=id[t], ib=id[ixj];
        bool aBefore = (va > vb) || (va == vb && ia < ib);
        bool up = ((t & k) == 0);
        if(up != aBefore){ v[t]=vb; v[ixj]=va; id[t]=ib; id[ixj]=ia; }
      }
      __syncthreads();
    }
  }
  __shared__ float tv[32];
  __shared__ int   ti[32];
  if(t<32){ tv[t]=v[t]; ti[t]=id[t]; }
  __syncthreads();
  const float* xb = x + (size_t)b*65536;
  float* ob = out + (size_t)(b*8+g)*8192;
  for(int i=t;i<8192;i+=256){
    int k=i>>8, pix=i&255;
    ob[i] = tv[k] * xb[ti[k]*256 + pix];
  }
}

// ---------------- launcher ----------------
extern "C" void kernel_launch(void* const* d_in, const int* in_sizes, int n_in,
                              void* d_out, int out_size, void* d_ws, size_t ws_size,
                              hipStream_t stream){
  const float* x = (const float*)d_in[0];
  float*  ws  = (float*)d_ws;
  double* dws = (double*)d_ws;
  float* out = (float*)d_out;
  float* assign_out = out + 1048576;

  const float* g1=(const float*)d_in[3];  const float* b1=(const float*)d_in[4];
  const float* g2=(const float*)d_in[7];  const float* b2=(const float*)d_in[8];
  const float* g3=(const float*)d_in[11]; const float* b3=(const float*)d_in[12];

  WP wp;
  const int map[18] = {1,2,5,6,9,10,13,14,15,16,17,18,19,20,21,22,23,24};
  for(int i=0;i<18;i++) wp.p[i] = (const float*)d_in[map[i]];

  k_zero <<<2162, 256, 0, stream>>>(dws + D_ACC1);
  k_cvt  <<<dim3(1024,18), 256, 0, stream>>>(wp, ws);
  k_p1   <<<4096, 256, 0, stream>>>(x, ws, dws+D_ACC1);
  k_fin  <<<32, 64, 0, stream>>>(dws+D_ACC1, 32, g1, b1, dws+D_AFF1);
  k_p2   <<<4096, 256, 0, stream>>>(x, ws, dws+D_AFF1, dws+D_ACC2);
  k_fin  <<<64, 64, 0, stream>>>(dws+D_ACC2, 64, g2, b2, dws+D_AFF2);
  k_p34<0><<<16384, 256, 0, stream>>>(x, ws, dws+D_AFF1, dws+D_AFF2, dws+D_AFF3, dws+D_ACC3);
  k_fin  <<<128, 64, 0, stream>>>(dws+D_ACC3, 128, g3, b3, dws+D_AFF3);
  k_p34<1><<<16384, 256, 0, stream>>>(x, ws, dws+D_AFF1, dws+D_AFF2, dws+D_AFF3, dws+D_FEAT);
  k_mlp  <<<1024, 256, 0, stream>>>(ws, dws+D_FEAT, assign_out);
  k_topk <<<128, 256, 0, stream>>>(assign_out, x, out);
}